// Round 7
// baseline (135.455 us; speedup 1.0000x reference)
//
#include <hip/hip_runtime.h>

#define B_   32
#define D_   256
#define HW_  1024
#define N_   32768
#define K_   1024
#define DHW  (D_ * HW_)      // 262144
#define MARGIN 0.3f

typedef __attribute__((ext_vector_type(8)))  short bf16x8;
typedef __attribute__((ext_vector_type(16))) float f32x16;

union FragU { uint4 q; bf16x8 v; };

__device__ inline uint bf16rne(float x) {
    uint ub = __float_as_uint(x);
    return (ub + 0x7fffu + ((ub >> 16) & 1u)) >> 16;
}

// ================= prep_cb: codebook -> d-outer hi/lo planes + csq; zero-init ====
// cbt2 layout (uint4): [ch 16][it 4][k 1024], it = p*2 + h; cell = 8 bf16 of plane p,
// d = ch*16 + h*8 + (0..7).
__global__ __launch_bounds__(256)
void prep_cb(const float* __restrict__ cb, uint4* __restrict__ cbt2,
             float* __restrict__ csq, int* __restrict__ rcount,
             float* __restrict__ oloss) {
    __shared__ uint sh[256], sl[256];
    __shared__ float rr[4];
    const int k = blockIdx.x, d = threadIdx.x;
    float v = cb[(size_t)k * D_ + d];
    uint hb = bf16rne(v);
    float hf = __uint_as_float(hb << 16);
    uint lb = bf16rne(v - hf);
    sh[d] = hb; sl[d] = lb;
    float s = v * v;
    #pragma unroll
    for (int off = 32; off >= 1; off >>= 1) s += __shfl_xor(s, off, 64);
    if ((d & 63) == 0) rr[d >> 6] = s;
    __syncthreads();
    if (d == 0) csq[k] = (rr[0] + rr[1]) + (rr[2] + rr[3]);
    if (k == 0 && d == 0) { *rcount = 0; oloss[0] = 0.f; oloss[1] = 0.f; }
    if (d < 64) {
        const int ch = d >> 2, it = d & 3;
        const int p = it >> 1, h = it & 1;
        const int d0 = ch * 16 + h * 8;
        const uint* src = p ? sl : sh;
        uint w[4];
        #pragma unroll
        for (int jj = 0; jj < 4; ++jj)
            w[jj] = src[d0 + 2 * jj] | (src[d0 + 2 * jj + 1] << 16);
        cbt2[((ch * 4 + it) << 10) + k] = make_uint4(w[0], w[1], w[2], w[3]);
    }
}

// ================= main: fused x staging + j4xf2 MFMA distances + argmin ==========
// 256 blocks x 512 thr. Block: 128 tokens x 1024 codes (2 tiles of 512).
// Wave wm in 0..7 owns 64 codes/tile; every wave covers all 128 tokens (j=0..3).
__global__ __launch_bounds__(512, 2)
void vq_main(const float* __restrict__ x, const uint4* __restrict__ cbt2,
             const float* __restrict__ csqg, int* __restrict__ bestk,
             int* __restrict__ rcount, int* __restrict__ rlist,
             float* __restrict__ bdist) {
    __shared__ uint4 TkS[32][128];     // 64 KB  [g=d/8][t]  (d-outer: reads contiguous)
    __shared__ uint4 CbS[2][4][512];   // 2x32 KB [buf][it=p*2+h][c]
    __shared__ float csqS[1024];       // 4 KB

    const int tid = threadIdx.x;
    const int lane = tid & 63;
    const int sub = lane >> 5, l31 = lane & 31;
    const int wm = tid >> 6;           // 0..7
    const int tok0 = blockIdx.x * 128;
    const int bb = tok0 >> 10, hw0 = tok0 & 1023;

    csqS[tid] = csqg[tid];
    csqS[tid + 512] = csqg[tid + 512];

    // ---- fused x -> bf16 staging into TkS[g][t] (contiguous ds_writes) ----
    {
        const int t = tid & 127;
        const int dgrp = tid >> 7;     // 0..3
        const float* xp = x + (size_t)bb * DHW + hw0 + t;
        #pragma unroll
        for (int i = 0; i < 8; ++i) {
            int g = i * 4 + dgrp;      // 0..31, d = 8g..8g+7
            float v[8];
            #pragma unroll
            for (int e = 0; e < 8; ++e)
                v[e] = xp[(size_t)(g * 8 + e) * HW_];
            uint w[4];
            #pragma unroll
            for (int jj = 0; jj < 4; ++jj)
                w[jj] = bf16rne(v[2 * jj]) | (bf16rne(v[2 * jj + 1]) << 16);
            TkS[g][t] = make_uint4(w[0], w[1], w[2], w[3]);
        }
    }
    asm volatile("s_waitcnt vmcnt(0) lgkmcnt(0)" ::: "memory");
    __syncthreads();

    // ---- stage iter 0 (ct=0, ch=0): wave-contiguous gld ----
    #pragma unroll
    for (int it = 0; it < 4; ++it) {
        const uint4* src = cbt2 + ((it << 10) + tid);
        __builtin_amdgcn_global_load_lds((const uint*)src, (uint*)&CbS[0][it][tid], 16, 0, 0);
    }

    f32x16 acc[2][4] = {};
    float v1[4], v2[4]; int k1[4];
    #pragma unroll
    for (int j = 0; j < 4; ++j) { v1[j] = 3.4e38f; v2[j] = 3.4e38f; k1[j] = 0; }

    int cur = 0;
    for (int cc = 0; cc < 32; ++cc) {
        const int ct = cc >> 4, ch = cc & 15;

        // token fragments: TkS is immutable -> read before the barriers (off critical path)
        FragU tf[4];
        #pragma unroll
        for (int j = 0; j < 4; ++j)
            tf[j].q = TkS[ch * 2 + sub][j * 32 + l31];

        asm volatile("s_barrier" ::: "memory");   // B1: all reads of buf[cur^1] done
        if (cc + 1 < 32) {
            const int nct = (cc + 1) >> 4, nch = (cc + 1) & 15;
            #pragma unroll
            for (int it = 0; it < 4; ++it) {
                const uint4* src = cbt2 + (((nch * 4 + it) << 10) + nct * 512 + tid);
                __builtin_amdgcn_global_load_lds((const uint*)src, (uint*)&CbS[cur ^ 1][it][tid], 16, 0, 0);
            }
            asm volatile("s_waitcnt vmcnt(4)" ::: "memory");  // this iter's 4 arrived
        } else {
            asm volatile("s_waitcnt vmcnt(0)" ::: "memory");
        }
        asm volatile("s_barrier" ::: "memory");   // B2: every wave's loads drained

        // code fragments: contiguous 512B reads, conflict-free
        FragU cfh[2], cfl[2];
        #pragma unroll
        for (int f = 0; f < 2; ++f) {
            int c = wm * 64 + f * 32 + l31;
            cfh[f].q = CbS[cur][sub][c];        // p=0 (hi), h=sub
            cfl[f].q = CbS[cur][2 + sub][c];    // p=1 (lo)
        }
        __builtin_amdgcn_s_setprio(1);
        #pragma unroll
        for (int f = 0; f < 2; ++f)
            #pragma unroll
            for (int j = 0; j < 4; ++j)
                acc[f][j] = __builtin_amdgcn_mfma_f32_32x32x16_bf16(cfh[f].v, tf[j].v, acc[f][j], 0, 0, 0);
        #pragma unroll
        for (int f = 0; f < 2; ++f)
            #pragma unroll
            for (int j = 0; j < 4; ++j)
                acc[f][j] = __builtin_amdgcn_mfma_f32_32x32x16_bf16(cfl[f].v, tf[j].v, acc[f][j], 0, 0, 0);
        __builtin_amdgcn_s_setprio(0);
        cur ^= 1;

        // ---- per-code-tile epilogue (after full 256-d sweep) ----
        if (ch == 15) {
            const int cbase = ct * 512 + wm * 64 + sub * 4;
            #pragma unroll
            for (int f = 0; f < 2; ++f) {
                #pragma unroll
                for (int g8 = 0; g8 < 4; ++g8) {
                    float4 cs4 = *reinterpret_cast<const float4*>(&csqS[cbase + f * 32 + g8 * 8]);
                    const float csa[4] = {cs4.x, cs4.y, cs4.z, cs4.w};
                    #pragma unroll
                    for (int q = 0; q < 4; ++q) {
                        int code = cbase + f * 32 + g8 * 8 + q;
                        int r = g8 * 4 + q;
                        #pragma unroll
                        for (int j = 0; j < 4; ++j) {
                            float s = fmaf(-2.f, acc[f][j][r], csa[q]);
                            bool c = s < v1[j];
                            v2[j] = c ? v1[j] : fminf(v2[j], s);
                            k1[j] = c ? code : k1[j];
                            v1[j] = c ? s : v1[j];
                        }
                    }
                }
            }
            const f32x16 zf = {};
            #pragma unroll
            for (int f = 0; f < 2; ++f)
                #pragma unroll
                for (int j = 0; j < 4; ++j) acc[f][j] = zf;
        }
    }

    // ---- merge sub halves (codes interleaved across sub) ----
    #pragma unroll
    for (int j = 0; j < 4; ++j) {
        float ov1 = __shfl_xor(v1[j], 32, 64);
        float ov2 = __shfl_xor(v2[j], 32, 64);
        int   ok1 = __shfl_xor(k1[j], 32, 64);
        float nv2 = fminf(fminf(v2[j], ov2), fmaxf(v1[j], ov1));
        if (ov1 < v1[j] || (ov1 == v1[j] && ok1 < k1[j])) { v1[j] = ov1; k1[j] = ok1; }
        v2[j] = nv2;
    }
    __syncthreads();
    float* red = (float*)&CbS[0][0][0];   // [8 wm][128 t][3]
    if (sub == 0) {
        #pragma unroll
        for (int j = 0; j < 4; ++j) {
            int t = j * 32 + l31;
            red[(wm * 128 + t) * 3 + 0] = v1[j];
            red[(wm * 128 + t) * 3 + 1] = v2[j];
            red[(wm * 128 + t) * 3 + 2] = __int_as_float(k1[j]);
        }
    }
    __syncthreads();
    if (tid < 128) {
        float bv1 = red[tid * 3], bv2 = red[tid * 3 + 1];
        int bk = __float_as_int(red[tid * 3 + 2]);
        #pragma unroll
        for (int m = 1; m < 8; ++m) {
            float a1 = red[(m * 128 + tid) * 3], a2 = red[(m * 128 + tid) * 3 + 1];
            int ak = __float_as_int(red[(m * 128 + tid) * 3 + 2]);
            float nv2 = fminf(fminf(bv2, a2), fmaxf(bv1, a1));
            if (a1 < bv1 || (a1 == bv1 && ak < bk)) { bv1 = a1; bk = ak; }
            bv2 = nv2;
        }
        int n = tok0 + tid;
        bestk[n] = bk;
        bdist[n] = bv1;
        if (bv2 - bv1 < MARGIN) rlist[atomicAdd(rcount, 1)] = n;
    }
}

// ================= exact fp32 refine: row-major cb, ILP-batched, 8-token batches ====
__global__ __launch_bounds__(256)
void vq_refine(const float* __restrict__ x, const float* __restrict__ cb,
               const float* __restrict__ csq, const int* __restrict__ rcount,
               const int* __restrict__ rlist, int* __restrict__ bestk,
               float* __restrict__ bdist) {
    __shared__ float xv[8][256];
    __shared__ float xsq[8];
    __shared__ float wredv[4][8];
    __shared__ int   wredk[4][8];
    const int tid = threadIdx.x;
    const int cnt = min(rcount[0], N_);
    for (int base = blockIdx.x * 8; base < cnt; base += gridDim.x * 8) {
        const int m = min(8, cnt - base);
        __syncthreads();
        for (int j = 0; j < m; ++j) {
            int n = rlist[base + j];
            int b = n >> 10, hw = n & 1023;
            xv[j][tid] = x[(size_t)b * DHW + (size_t)tid * HW_ + hw];
        }
        for (int j = m; j < 8; ++j) xv[j][tid] = 0.f;
        __syncthreads();
        {   // xsq: 8 groups of 32 lanes
            int g = tid >> 5, l = tid & 31;
            float s = 0.f;
            #pragma unroll
            for (int d8 = 0; d8 < 8; ++d8) { float v = xv[g][d8 * 32 + l]; s = fmaf(v, v, s); }
            #pragma unroll
            for (int mm = 1; mm < 32; mm <<= 1) s += __shfl_xor(s, mm, 64);
            if (l == 0) xsq[g] = s;
        }
        __syncthreads();

        float dots[4][8];
        #pragma unroll
        for (int c4 = 0; c4 < 4; ++c4)
            #pragma unroll
            for (int j = 0; j < 8; ++j) dots[c4][j] = 0.f;

        for (int d0 = 0; d0 < 256; d0 += 8) {
            float xr[8][8];
            #pragma unroll
            for (int j = 0; j < 8; ++j) {
                float4 a = *reinterpret_cast<const float4*>(&xv[j][d0]);
                float4 b = *reinterpret_cast<const float4*>(&xv[j][d0 + 4]);
                xr[j][0] = a.x; xr[j][1] = a.y; xr[j][2] = a.z; xr[j][3] = a.w;
                xr[j][4] = b.x; xr[j][5] = b.y; xr[j][6] = b.z; xr[j][7] = b.w;
            }
            #pragma unroll
            for (int c4 = 0; c4 < 4; ++c4) {
                const float4* cr = reinterpret_cast<const float4*>(
                    cb + (size_t)(c4 * 256 + tid) * D_ + d0);
                float4 ca = cr[0], cbv = cr[1];
                float cv[8] = { ca.x, ca.y, ca.z, ca.w, cbv.x, cbv.y, cbv.z, cbv.w };
                #pragma unroll
                for (int u = 0; u < 8; ++u)
                    #pragma unroll
                    for (int j = 0; j < 8; ++j)
                        dots[c4][j] = fmaf(cv[u], xr[j][u], dots[c4][j]);
            }
        }

        float bv[8]; int bk[8];
        #pragma unroll
        for (int j = 0; j < 8; ++j) { bv[j] = 3.4e38f; bk[j] = 0; }
        #pragma unroll
        for (int c4 = 0; c4 < 4; ++c4) {
            const int code = c4 * 256 + tid;
            const float cs = csq[code];
            #pragma unroll
            for (int j = 0; j < 8; ++j) {
                float dist = fmaf(-2.f, dots[c4][j], xsq[j]) + cs;
                if (dist < bv[j]) { bv[j] = dist; bk[j] = code; }
            }
        }
        #pragma unroll
        for (int j = 0; j < 8; ++j) {
            if (j < m) {
                float v = bv[j]; int k = bk[j];
                #pragma unroll
                for (int mm = 1; mm < 64; mm <<= 1) {
                    float ov = __shfl_xor(v, mm, 64);
                    int   ok = __shfl_xor(k, mm, 64);
                    if (ov < v || (ov == v && ok < k)) { v = ov; k = ok; }
                }
                if ((tid & 63) == 0) { wredv[tid >> 6][j] = v; wredk[tid >> 6][j] = k; }
            }
        }
        __syncthreads();
        if (tid < m) {
            float v = wredv[0][tid]; int k = wredk[0][tid];
            #pragma unroll
            for (int q = 1; q < 4; ++q) {
                if (wredv[q][tid] < v || (wredv[q][tid] == v && wredk[q][tid] < k)) {
                    v = wredv[q][tid]; k = wredk[q][tid];
                }
            }
            int n = rlist[base + tid];
            bestk[n] = k;
            bdist[n] = v;
        }
        __syncthreads();
    }
}

// ================= gather codewords (float4 stores), write out/idx, fused loss ====
__global__ __launch_bounds__(256)
void vq_gather(const float* __restrict__ cb, const int* __restrict__ bestk,
               const float* __restrict__ bdist, float* __restrict__ out,
               float* __restrict__ oidx, float* __restrict__ oloss) {
    const int n0 = blockIdx.x * 64;
    const int tid = threadIdx.x;
    const int j16 = tid & 15, dg = tid >> 4;        // 16 hw-quads x 16 d-groups
    const int bb = n0 >> 10, hw0 = n0 & 1023;
    int k4[4];
    #pragma unroll
    for (int e = 0; e < 4; ++e) k4[e] = bestk[n0 + j16 * 4 + e];
    const size_t obase = (size_t)bb * DHW + hw0 + j16 * 4;
    #pragma unroll 4
    for (int d = dg * 16; d < dg * 16 + 16; ++d) {
        float4 w;
        w.x = cb[(size_t)k4[0] * D_ + d];
        w.y = cb[(size_t)k4[1] * D_ + d];
        w.z = cb[(size_t)k4[2] * D_ + d];
        w.w = cb[(size_t)k4[3] * D_ + d];
        *reinterpret_cast<float4*>(out + obase + (size_t)d * HW_) = w;
    }
    if (tid < 64) {
        oidx[n0 + tid] = (float)bestk[n0 + tid];
        float v = bdist[n0 + tid];
        #pragma unroll
        for (int off = 32; off >= 1; off >>= 1) v += __shfl_xor(v, off, 64);
        if (tid == 0) {
            float t = v * (1.0f / 8388608.0f);   // / (N*D)
            atomicAdd(&oloss[0], t);
            atomicAdd(&oloss[1], t);
        }
    }
}

extern "C" void kernel_launch(void* const* d_in, const int* in_sizes, int n_in,
                              void* d_out, int out_size, void* d_ws, size_t ws_size,
                              hipStream_t stream) {
    const float* x  = (const float*)d_in[0];
    const float* cb = (const float*)d_in[1];

    float* out   = (float*)d_out;            // 8388608 floats
    float* oidx  = out + 8388608;            // 32768 floats
    float* oloss = out + 8388608 + 32768;    // 2 floats

    uint* wsb = (uint*)d_ws;
    uint4*  cbt2  = (uint4*)wsb;             // 65536 uint4 (1 MB)
    float*  csq   = (float*)(wsb + 262144);  // 1024
    int*    bestk = (int*)  (wsb + 263168);  // 32768
    int*    rcount= (int*)  (wsb + 295936);  // 1
    int*    rlist = (int*)  (wsb + 295940);  // 32768
    float*  bdist = (float*)(wsb + 328708);  // 32768

    prep_cb <<<1024, 256, 0, stream>>>(cb, cbt2, csq, rcount, oloss);
    vq_main <<<256, 512, 0, stream>>>(x, cbt2, csq, bestk, rcount, rlist, bdist);
    vq_refine<<<256, 256, 0, stream>>>(x, cb, csq, rcount, rlist, bestk, bdist);
    vq_gather<<<512, 256, 0, stream>>>(cb, bestk, bdist, out, oidx, oloss);
}

// Round 8
// 135.381 us; speedup vs baseline: 1.0005x; 1.0005x over previous
//
#include <hip/hip_runtime.h>

#define B_   32
#define D_   256
#define HW_  1024
#define N_   32768
#define K_   1024
#define DHW  (D_ * HW_)      // 262144
#define MARGIN 0.3f

typedef __attribute__((ext_vector_type(8)))  short bf16x8;
typedef __attribute__((ext_vector_type(16))) float f32x16;

union FragU { uint4 q; bf16x8 v; };

__device__ inline uint bf16rne(float x) {
    uint ub = __float_as_uint(x);
    return (ub + 0x7fffu + ((ub >> 16) & 1u)) >> 16;
}

// ================= prep_cb: codebook -> d-outer hi/lo planes + csq; zero-init ====
// cbt2 layout (uint4): [ch 16][it 4][k 1024], it = p*2 + h; cell = 8 bf16 of plane p,
// d = ch*16 + h*8 + (0..7).
__global__ __launch_bounds__(256)
void prep_cb(const float* __restrict__ cb, uint4* __restrict__ cbt2,
             float* __restrict__ csq, int* __restrict__ rcount,
             float* __restrict__ oloss) {
    __shared__ uint sh[256], sl[256];
    __shared__ float rr[4];
    const int k = blockIdx.x, d = threadIdx.x;
    float v = cb[(size_t)k * D_ + d];
    uint hb = bf16rne(v);
    float hf = __uint_as_float(hb << 16);
    uint lb = bf16rne(v - hf);
    sh[d] = hb; sl[d] = lb;
    float s = v * v;
    #pragma unroll
    for (int off = 32; off >= 1; off >>= 1) s += __shfl_xor(s, off, 64);
    if ((d & 63) == 0) rr[d >> 6] = s;
    __syncthreads();
    if (d == 0) csq[k] = (rr[0] + rr[1]) + (rr[2] + rr[3]);
    if (k == 0 && d == 0) { *rcount = 0; oloss[0] = 0.f; oloss[1] = 0.f; }
    if (d < 64) {
        const int ch = d >> 2, it = d & 3;
        const int p = it >> 1, h = it & 1;
        const int d0 = ch * 16 + h * 8;
        const uint* src = p ? sl : sh;
        uint w[4];
        #pragma unroll
        for (int jj = 0; jj < 4; ++jj)
            w[jj] = src[d0 + 2 * jj] | (src[d0 + 2 * jj + 1] << 16);
        cbt2[((ch * 4 + it) << 10) + k] = make_uint4(w[0], w[1], w[2], w[3]);
    }
}

// ================= main: 64-token blocks (2/CU), fused gather+loss ==========
// 512 blocks x 256 thr. Block: 64 tokens x 1024 codes (4 tiles of 256).
// Wave wm in 0..3 owns 64 codes/tile; every wave covers all 64 tokens (j=0..1).
__global__ __launch_bounds__(256, 2)
void vq_main(const float* __restrict__ x, const uint4* __restrict__ cbt2,
             const float* __restrict__ csqg, const float* __restrict__ cb,
             int* __restrict__ rcount, int* __restrict__ rlist,
             float* __restrict__ bdist, float* __restrict__ out,
             float* __restrict__ oidx, float* __restrict__ oloss) {
    __shared__ uint4 TkS[32][64];      // 32 KB  [g=d/8][t]
    __shared__ uint4 CbS[2][4][256];   // 2x16 KB [buf][it=p*2+h][c]
    __shared__ float csqS[1024];       // 4 KB

    const int tid = threadIdx.x;
    const int lane = tid & 63;
    const int sub = lane >> 5, l31 = lane & 31;
    const int wm = tid >> 6;           // 0..3
    const int tok0 = blockIdx.x * 64;
    const int bb = tok0 >> 10, hw0 = tok0 & 1023;

    #pragma unroll
    for (int q = 0; q < 4; ++q) csqS[q * 256 + tid] = csqg[q * 256 + tid];

    // ---- fused x -> bf16 staging into TkS[g][t] ----
    {
        const int t = tid & 63;
        const int dgrp = tid >> 6;     // 0..3 (wave-uniform)
        const float* xp = x + (size_t)bb * DHW + hw0 + t;
        #pragma unroll
        for (int i = 0; i < 8; ++i) {
            int g = i * 4 + dgrp;      // 0..31, d = 8g..8g+7
            float v[8];
            #pragma unroll
            for (int e = 0; e < 8; ++e)
                v[e] = xp[(size_t)(g * 8 + e) * HW_];
            uint w[4];
            #pragma unroll
            for (int jj = 0; jj < 4; ++jj)
                w[jj] = bf16rne(v[2 * jj]) | (bf16rne(v[2 * jj + 1]) << 16);
            TkS[g][t] = make_uint4(w[0], w[1], w[2], w[3]);
        }
    }
    asm volatile("s_waitcnt vmcnt(0) lgkmcnt(0)" ::: "memory");
    __syncthreads();

    // ---- stage iter 0 (ct=0, ch=0) ----
    #pragma unroll
    for (int it = 0; it < 4; ++it) {
        const uint4* src = cbt2 + ((it << 10) + tid);
        __builtin_amdgcn_global_load_lds((const uint*)src, (uint*)&CbS[0][it][tid], 16, 0, 0);
    }

    f32x16 acc[2][2] = {};
    float v1[2] = {3.4e38f, 3.4e38f}, v2[2] = {3.4e38f, 3.4e38f};
    int k1[2] = {0, 0};

    int cur = 0;
    for (int cc = 0; cc < 64; ++cc) {
        const int ct = cc >> 4, ch = cc & 15;

        // token fragments (TkS immutable -> off the critical path)
        FragU tf[2];
        #pragma unroll
        for (int j = 0; j < 2; ++j)
            tf[j].q = TkS[ch * 2 + sub][j * 32 + l31];

        asm volatile("s_barrier" ::: "memory");   // B1: reads of buf[cur^1] done
        if (cc + 1 < 64) {
            const int nct = (cc + 1) >> 4, nch = (cc + 1) & 15;
            #pragma unroll
            for (int it = 0; it < 4; ++it) {
                const uint4* src = cbt2 + (((nch * 4 + it) << 10) + nct * 256 + tid);
                __builtin_amdgcn_global_load_lds((const uint*)src, (uint*)&CbS[cur ^ 1][it][tid], 16, 0, 0);
            }
            asm volatile("s_waitcnt vmcnt(4)" ::: "memory");  // this iter's 4 arrived
        } else {
            asm volatile("s_waitcnt vmcnt(0)" ::: "memory");
        }
        asm volatile("s_barrier" ::: "memory");   // B2: every wave's loads drained

        FragU cfh[2], cfl[2];
        #pragma unroll
        for (int f = 0; f < 2; ++f) {
            int c = wm * 64 + f * 32 + l31;
            cfh[f].q = CbS[cur][sub][c];        // p=0 (hi)
            cfl[f].q = CbS[cur][2 + sub][c];    // p=1 (lo)
        }
        __builtin_amdgcn_s_setprio(1);
        #pragma unroll
        for (int f = 0; f < 2; ++f)
            #pragma unroll
            for (int j = 0; j < 2; ++j)
                acc[f][j] = __builtin_amdgcn_mfma_f32_32x32x16_bf16(cfh[f].v, tf[j].v, acc[f][j], 0, 0, 0);
        #pragma unroll
        for (int f = 0; f < 2; ++f)
            #pragma unroll
            for (int j = 0; j < 2; ++j)
                acc[f][j] = __builtin_amdgcn_mfma_f32_32x32x16_bf16(cfl[f].v, tf[j].v, acc[f][j], 0, 0, 0);
        __builtin_amdgcn_s_setprio(0);
        cur ^= 1;

        // ---- per-code-tile epilogue (after full 256-d sweep) ----
        if (ch == 15) {
            const int cbase = ct * 256 + wm * 64 + sub * 4;
            #pragma unroll
            for (int f = 0; f < 2; ++f) {
                #pragma unroll
                for (int g8 = 0; g8 < 4; ++g8) {
                    float4 cs4 = *reinterpret_cast<const float4*>(&csqS[cbase + f * 32 + g8 * 8]);
                    const float csa[4] = {cs4.x, cs4.y, cs4.z, cs4.w};
                    #pragma unroll
                    for (int q = 0; q < 4; ++q) {
                        int code = cbase + f * 32 + g8 * 8 + q;
                        int r = g8 * 4 + q;
                        #pragma unroll
                        for (int j = 0; j < 2; ++j) {
                            float s = fmaf(-2.f, acc[f][j][r], csa[q]);
                            bool c = s < v1[j];
                            v2[j] = c ? v1[j] : fminf(v2[j], s);
                            k1[j] = c ? code : k1[j];
                            v1[j] = c ? s : v1[j];
                        }
                    }
                }
            }
            const f32x16 zf = {};
            #pragma unroll
            for (int f = 0; f < 2; ++f)
                #pragma unroll
                for (int j = 0; j < 2; ++j) acc[f][j] = zf;
        }
    }

    // ---- merge sub halves ----
    #pragma unroll
    for (int j = 0; j < 2; ++j) {
        float ov1 = __shfl_xor(v1[j], 32, 64);
        float ov2 = __shfl_xor(v2[j], 32, 64);
        int   ok1 = __shfl_xor(k1[j], 32, 64);
        float nv2 = fminf(fminf(v2[j], ov2), fmaxf(v1[j], ov1));
        if (ov1 < v1[j] || (ov1 == v1[j] && ok1 < k1[j])) { v1[j] = ov1; k1[j] = ok1; }
        v2[j] = nv2;
    }
    __syncthreads();
    float* red = (float*)&CbS[0][0][0];       // [4 wm][64 t][3] = 768 floats
    int* bestk_s = (int*)(red + 768);         // 64 ints
    if (sub == 0) {
        #pragma unroll
        for (int j = 0; j < 2; ++j) {
            int t = j * 32 + l31;
            red[(wm * 64 + t) * 3 + 0] = v1[j];
            red[(wm * 64 + t) * 3 + 1] = v2[j];
            red[(wm * 64 + t) * 3 + 2] = __int_as_float(k1[j]);
        }
    }
    __syncthreads();
    if (tid < 64) {
        float bv1 = red[tid * 3], bv2 = red[tid * 3 + 1];
        int bk = __float_as_int(red[tid * 3 + 2]);
        #pragma unroll
        for (int m = 1; m < 4; ++m) {
            float a1 = red[(m * 64 + tid) * 3], a2 = red[(m * 64 + tid) * 3 + 1];
            int ak = __float_as_int(red[(m * 64 + tid) * 3 + 2]);
            float nv2 = fminf(fminf(bv2, a2), fmaxf(bv1, a1));
            if (a1 < bv1 || (a1 == bv1 && ak < bk)) { bv1 = a1; bk = ak; }
            bv2 = nv2;
        }
        int n = tok0 + tid;
        bestk_s[tid] = bk;
        bdist[n] = bv1;
        oidx[n] = (float)bk;
        if (bv2 - bv1 < MARGIN) rlist[atomicAdd(rcount, 1)] = n;
        // block loss contribution
        float v = bv1;
        #pragma unroll
        for (int off = 32; off >= 1; off >>= 1) v += __shfl_xor(v, off, 64);
        if (tid == 0) {
            float t2 = v * (1.0f / 8388608.0f);
            atomicAdd(&oloss[0], t2);
            atomicAdd(&oloss[1], t2);
        }
    }
    __syncthreads();

    // ---- fused gather: 64 tokens x 256 d ----
    {
        const int j16 = tid & 15, dg = tid >> 4;   // 16 token-quads x 16 d-groups
        int k4[4];
        #pragma unroll
        for (int e = 0; e < 4; ++e) k4[e] = bestk_s[j16 * 4 + e];
        const size_t obase = (size_t)bb * DHW + hw0 + j16 * 4;
        #pragma unroll 4
        for (int d = dg * 16; d < dg * 16 + 16; ++d) {
            float4 w;
            w.x = cb[(size_t)k4[0] * D_ + d];
            w.y = cb[(size_t)k4[1] * D_ + d];
            w.z = cb[(size_t)k4[2] * D_ + d];
            w.w = cb[(size_t)k4[3] * D_ + d];
            *reinterpret_cast<float4*>(out + obase + (size_t)d * HW_) = w;
        }
    }
}

// ================= exact fp32 refine + fix-up of out/oidx/loss ==========
__global__ __launch_bounds__(256)
void vq_refine(const float* __restrict__ x, const float* __restrict__ cb,
               const float* __restrict__ csq, const int* __restrict__ rcount,
               const int* __restrict__ rlist, const float* __restrict__ bdist,
               float* __restrict__ out, float* __restrict__ oidx,
               float* __restrict__ oloss) {
    __shared__ float xv[8][256];
    __shared__ float xsq[8];
    __shared__ float wredv[4][8];
    __shared__ int   wredk[4][8];
    __shared__ int   kfin[8];
    const int tid = threadIdx.x;
    const int cnt = min(rcount[0], N_);
    for (int base = blockIdx.x * 8; base < cnt; base += gridDim.x * 8) {
        const int m = min(8, cnt - base);
        __syncthreads();
        for (int j = 0; j < m; ++j) {
            int n = rlist[base + j];
            int b = n >> 10, hw = n & 1023;
            xv[j][tid] = x[(size_t)b * DHW + (size_t)tid * HW_ + hw];
        }
        for (int j = m; j < 8; ++j) xv[j][tid] = 0.f;
        __syncthreads();
        {   // xsq: 8 groups of 32 lanes
            int g = tid >> 5, l = tid & 31;
            float s = 0.f;
            #pragma unroll
            for (int d8 = 0; d8 < 8; ++d8) { float v = xv[g][d8 * 32 + l]; s = fmaf(v, v, s); }
            #pragma unroll
            for (int mm = 1; mm < 32; mm <<= 1) s += __shfl_xor(s, mm, 64);
            if (l == 0) xsq[g] = s;
        }
        __syncthreads();

        float dots[4][8];
        #pragma unroll
        for (int c4 = 0; c4 < 4; ++c4)
            #pragma unroll
            for (int j = 0; j < 8; ++j) dots[c4][j] = 0.f;

        for (int d0 = 0; d0 < 256; d0 += 8) {
            float xr[8][8];
            #pragma unroll
            for (int j = 0; j < 8; ++j) {
                float4 a = *reinterpret_cast<const float4*>(&xv[j][d0]);
                float4 b = *reinterpret_cast<const float4*>(&xv[j][d0 + 4]);
                xr[j][0] = a.x; xr[j][1] = a.y; xr[j][2] = a.z; xr[j][3] = a.w;
                xr[j][4] = b.x; xr[j][5] = b.y; xr[j][6] = b.z; xr[j][7] = b.w;
            }
            #pragma unroll
            for (int c4 = 0; c4 < 4; ++c4) {
                const float4* cr = reinterpret_cast<const float4*>(
                    cb + (size_t)(c4 * 256 + tid) * D_ + d0);
                float4 ca = cr[0], cbv = cr[1];
                float cv[8] = { ca.x, ca.y, ca.z, ca.w, cbv.x, cbv.y, cbv.z, cbv.w };
                #pragma unroll
                for (int u = 0; u < 8; ++u)
                    #pragma unroll
                    for (int j = 0; j < 8; ++j)
                        dots[c4][j] = fmaf(cv[u], xr[j][u], dots[c4][j]);
            }
        }

        float bv[8]; int bk[8];
        #pragma unroll
        for (int j = 0; j < 8; ++j) { bv[j] = 3.4e38f; bk[j] = 0; }
        #pragma unroll
        for (int c4 = 0; c4 < 4; ++c4) {
            const int code = c4 * 256 + tid;
            const float cs = csq[code];
            #pragma unroll
            for (int j = 0; j < 8; ++j) {
                float dist = fmaf(-2.f, dots[c4][j], xsq[j]) + cs;
                if (dist < bv[j]) { bv[j] = dist; bk[j] = code; }
            }
        }
        #pragma unroll
        for (int j = 0; j < 8; ++j) {
            if (j < m) {
                float v = bv[j]; int k = bk[j];
                #pragma unroll
                for (int mm = 1; mm < 64; mm <<= 1) {
                    float ov = __shfl_xor(v, mm, 64);
                    int   ok = __shfl_xor(k, mm, 64);
                    if (ov < v || (ov == v && ok < k)) { v = ov; k = ok; }
                }
                if ((tid & 63) == 0) { wredv[tid >> 6][j] = v; wredk[tid >> 6][j] = k; }
            }
        }
        __syncthreads();
        if (tid < m) {
            float v = wredv[0][tid]; int k = wredk[0][tid];
            #pragma unroll
            for (int q = 1; q < 4; ++q) {
                if (wredv[q][tid] < v || (wredv[q][tid] == v && wredk[q][tid] < k)) {
                    v = wredv[q][tid]; k = wredk[q][tid];
                }
            }
            int n = rlist[base + tid];
            kfin[tid] = k;
            oidx[n] = (float)k;
            float delta = (v - bdist[n]) * (1.0f / 8388608.0f);
            atomicAdd(&oloss[0], delta);
            atomicAdd(&oloss[1], delta);
        }
        __syncthreads();
        // rewrite out rows for corrected tokens (256 thr = one d each)
        for (int j = 0; j < m; ++j) {
            int n = rlist[base + j];
            int b = n >> 10, hw = n & 1023;
            out[(size_t)b * DHW + (size_t)tid * HW_ + hw] = cb[(size_t)kfin[j] * D_ + tid];
        }
        __syncthreads();
    }
}

extern "C" void kernel_launch(void* const* d_in, const int* in_sizes, int n_in,
                              void* d_out, int out_size, void* d_ws, size_t ws_size,
                              hipStream_t stream) {
    const float* x  = (const float*)d_in[0];
    const float* cb = (const float*)d_in[1];

    float* out   = (float*)d_out;            // 8388608 floats
    float* oidx  = out + 8388608;            // 32768 floats
    float* oloss = out + 8388608 + 32768;    // 2 floats

    uint* wsb = (uint*)d_ws;
    uint4*  cbt2  = (uint4*)wsb;             // 65536 uint4 (1 MB)
    float*  csq   = (float*)(wsb + 262144);  // 1024
    int*    rcount= (int*)  (wsb + 263168);  // 1
    int*    rlist = (int*)  (wsb + 263172);  // 32768
    float*  bdist = (float*)(wsb + 295940);  // 32768

    prep_cb <<<1024, 256, 0, stream>>>(cb, cbt2, csq, rcount, oloss);
    vq_main <<<512, 256, 0, stream>>>(x, cbt2, csq, cb, rcount, rlist, bdist, out, oidx, oloss);
    vq_refine<<<256, 256, 0, stream>>>(x, cb, csq, rcount, rlist, bdist, out, oidx, oloss);
}

// Round 9
// 123.077 us; speedup vs baseline: 1.1006x; 1.1000x over previous
//
#include <hip/hip_runtime.h>

#define B_   32
#define D_   256
#define HW_  1024
#define N_   32768
#define K_   1024
#define DHW  (D_ * HW_)      // 262144
#define MARGIN 0.3f

typedef __attribute__((ext_vector_type(8)))  short bf16x8;
typedef __attribute__((ext_vector_type(16))) float f32x16;

union FragU { uint4 q; bf16x8 v; };

__device__ inline uint bf16rne(float x) {
    uint ub = __float_as_uint(x);
    return (ub + 0x7fffu + ((ub >> 16) & 1u)) >> 16;
}

// ================= prep_cb: codebook -> d-outer hi/lo planes + csq; zero-init ====
// cbt2 layout (uint4): [ch 16][it 4][k 1024], it = p*2 + h; cell = 8 bf16 of plane p,
// d = ch*16 + h*8 + (0..7).
__global__ __launch_bounds__(256)
void prep_cb(const float* __restrict__ cb, uint4* __restrict__ cbt2,
             float* __restrict__ csq, int* __restrict__ rcount,
             float* __restrict__ oloss) {
    __shared__ uint sh[256], sl[256];
    __shared__ float rr[4];
    const int k = blockIdx.x, d = threadIdx.x;
    float v = cb[(size_t)k * D_ + d];
    uint hb = bf16rne(v);
    float hf = __uint_as_float(hb << 16);
    uint lb = bf16rne(v - hf);
    sh[d] = hb; sl[d] = lb;
    float s = v * v;
    #pragma unroll
    for (int off = 32; off >= 1; off >>= 1) s += __shfl_xor(s, off, 64);
    if ((d & 63) == 0) rr[d >> 6] = s;
    __syncthreads();
    if (d == 0) csq[k] = (rr[0] + rr[1]) + (rr[2] + rr[3]);
    if (k == 0 && d == 0) { *rcount = 0; oloss[0] = 0.f; oloss[1] = 0.f; }
    if (d < 64) {
        const int ch = d >> 2, it = d & 3;
        const int p = it >> 1, h = it & 1;
        const int d0 = ch * 16 + h * 8;
        const uint* src = p ? sl : sh;
        uint w[4];
        #pragma unroll
        for (int jj = 0; jj < 4; ++jj)
            w[jj] = src[d0 + 2 * jj] | (src[d0 + 2 * jj + 1] << 16);
        cbt2[((ch * 4 + it) << 10) + k] = make_uint4(w[0], w[1], w[2], w[3]);
    }
}

// ================= main: barrier-free K-loop, codes direct from L2 ==========
// 256 blocks x 512 thr. Block: 128 tokens x 1024 codes. Wave w owns codes
// [w*128, w*128+128) (2 ct-halves of 64); tokens shared (j=0..3), in LDS.
__global__ __launch_bounds__(512)
void vq_main(const float* __restrict__ x, const uint4* __restrict__ cbt2,
             const float* __restrict__ csqg, const float* __restrict__ cb,
             int* __restrict__ rcount, int* __restrict__ rlist,
             float* __restrict__ bdist, float* __restrict__ out,
             float* __restrict__ oidx, float* __restrict__ oloss) {
    __shared__ uint4 TkS[32][128];     // 64 KB  [g=d/8][t]
    __shared__ float csqS[1024];       // 4 KB

    const int tid = threadIdx.x;
    const int lane = tid & 63;
    const int sub = lane >> 5, l31 = lane & 31;
    const int w = tid >> 6;            // 0..7
    const int tok0 = blockIdx.x * 128;
    const int bb = tok0 >> 10, hw0 = tok0 & 1023;

    csqS[tid] = csqg[tid];
    csqS[tid + 512] = csqg[tid + 512];

    // ---- fused x -> bf16 staging into TkS[g][t] ----
    {
        const int t = tid & 127;
        const int dgrp = tid >> 7;     // 0..3 (wave-uniform)
        const float* xp = x + (size_t)bb * DHW + hw0 + t;
        #pragma unroll
        for (int i = 0; i < 8; ++i) {
            int g = i * 4 + dgrp;      // 0..31, d = 8g..8g+7
            float v[8];
            #pragma unroll
            for (int e = 0; e < 8; ++e)
                v[e] = xp[(size_t)(g * 8 + e) * HW_];
            uint wd[4];
            #pragma unroll
            for (int jj = 0; jj < 4; ++jj)
                wd[jj] = bf16rne(v[2 * jj]) | (bf16rne(v[2 * jj + 1]) << 16);
            TkS[g][t] = make_uint4(wd[0], wd[1], wd[2], wd[3]);
        }
    }
    __syncthreads();   // only block-wide barrier before the epilogue

    f32x16 acc[2][4] = {};
    float v1[4], v2[4]; int k1[4];
    #pragma unroll
    for (int j = 0; j < 4; ++j) { v1[j] = 3.4e38f; v2[j] = 3.4e38f; k1[j] = 0; }

    // per-thread base for direct code loads: lane's k-slot plane base
    const uint4* cb_hi = cbt2 + (sub << 10) + w * 128 + l31;        // it = sub   (hi)
    const uint4* cb_lo = cbt2 + ((2 + sub) << 10) + w * 128 + l31;  // it = 2+sub (lo)

    for (int ct = 0; ct < 2; ++ct) {
        #pragma unroll 4
        for (int ch = 0; ch < 16; ++ch) {
            // code fragments direct from L2 (no inter-wave reuse -> no LDS)
            FragU cfh[2], cfl[2];
            #pragma unroll
            for (int f = 0; f < 2; ++f) {
                int off = ((ch * 4) << 10) + ct * 64 + f * 32;
                cfh[f].q = cb_hi[off];
                cfl[f].q = cb_lo[off];
            }
            // token fragments from LDS (8-way wave reuse)
            FragU tf[4];
            #pragma unroll
            for (int j = 0; j < 4; ++j)
                tf[j].q = TkS[ch * 2 + sub][j * 32 + l31];

            #pragma unroll
            for (int f = 0; f < 2; ++f)
                #pragma unroll
                for (int j = 0; j < 4; ++j)
                    acc[f][j] = __builtin_amdgcn_mfma_f32_32x32x16_bf16(cfh[f].v, tf[j].v, acc[f][j], 0, 0, 0);
            #pragma unroll
            for (int f = 0; f < 2; ++f)
                #pragma unroll
                for (int j = 0; j < 4; ++j)
                    acc[f][j] = __builtin_amdgcn_mfma_f32_32x32x16_bf16(cfl[f].v, tf[j].v, acc[f][j], 0, 0, 0);
        }

        // ---- per-ct epilogue: scores + per-lane running top-2 ----
        const int cbase = w * 128 + ct * 64 + sub * 4;
        #pragma unroll
        for (int f = 0; f < 2; ++f) {
            #pragma unroll
            for (int g8 = 0; g8 < 4; ++g8) {
                float4 cs4 = *reinterpret_cast<const float4*>(&csqS[cbase + f * 32 + g8 * 8]);
                const float csa[4] = {cs4.x, cs4.y, cs4.z, cs4.w};
                #pragma unroll
                for (int q = 0; q < 4; ++q) {
                    int code = cbase + f * 32 + g8 * 8 + q;
                    int r = g8 * 4 + q;
                    #pragma unroll
                    for (int j = 0; j < 4; ++j) {
                        float s = fmaf(-2.f, acc[f][j][r], csa[q]);
                        bool c = s < v1[j];
                        v2[j] = c ? v1[j] : fminf(v2[j], s);
                        k1[j] = c ? code : k1[j];
                        v1[j] = c ? s : v1[j];
                    }
                }
            }
        }
        const f32x16 zf = {};
        #pragma unroll
        for (int f = 0; f < 2; ++f)
            #pragma unroll
            for (int j = 0; j < 4; ++j) acc[f][j] = zf;
    }

    // ---- merge sub halves (codes interleaved across sub) ----
    #pragma unroll
    for (int j = 0; j < 4; ++j) {
        float ov1 = __shfl_xor(v1[j], 32, 64);
        float ov2 = __shfl_xor(v2[j], 32, 64);
        int   ok1 = __shfl_xor(k1[j], 32, 64);
        float nv2 = fminf(fminf(v2[j], ov2), fmaxf(v1[j], ov1));
        if (ov1 < v1[j] || (ov1 == v1[j] && ok1 < k1[j])) { v1[j] = ov1; k1[j] = ok1; }
        v2[j] = nv2;
    }
    __syncthreads();
    float* red = (float*)&TkS[0][0];          // [8 w][128 t][3] = 3072 floats
    int* bestk_s = (int*)(red + 3072);        // 128 ints
    if (sub == 0) {
        #pragma unroll
        for (int j = 0; j < 4; ++j) {
            int t = j * 32 + l31;
            red[(w * 128 + t) * 3 + 0] = v1[j];
            red[(w * 128 + t) * 3 + 1] = v2[j];
            red[(w * 128 + t) * 3 + 2] = __int_as_float(k1[j]);
        }
    }
    __syncthreads();
    if (tid < 128) {
        float bv1 = red[tid * 3], bv2 = red[tid * 3 + 1];
        int bk = __float_as_int(red[tid * 3 + 2]);
        #pragma unroll
        for (int m = 1; m < 8; ++m) {
            float a1 = red[(m * 128 + tid) * 3], a2 = red[(m * 128 + tid) * 3 + 1];
            int ak = __float_as_int(red[(m * 128 + tid) * 3 + 2]);
            float nv2 = fminf(fminf(bv2, a2), fmaxf(bv1, a1));
            if (a1 < bv1 || (a1 == bv1 && ak < bk)) { bv1 = a1; bk = ak; }
            bv2 = nv2;
        }
        int n = tok0 + tid;
        bestk_s[tid] = bk;
        bdist[n] = bv1;
        oidx[n] = (float)bk;
        if (bv2 - bv1 < MARGIN) rlist[atomicAdd(rcount, 1)] = n;
        float v = bv1;
        #pragma unroll
        for (int off = 32; off >= 1; off >>= 1) v += __shfl_xor(v, off, 64);
        if ((tid & 63) == 0) {
            float t2 = v * (1.0f / 8388608.0f);
            atomicAdd(&oloss[0], t2);
            atomicAdd(&oloss[1], t2);
        }
    }
    __syncthreads();

    // ---- fused gather: 128 tokens x 256 d ----
    {
        const int j32 = tid & 31, dg = tid >> 5;   // 32 token-quads x 16 d-groups
        int k4[4];
        #pragma unroll
        for (int e = 0; e < 4; ++e) k4[e] = bestk_s[j32 * 4 + e];
        const size_t obase = (size_t)bb * DHW + hw0 + j32 * 4;
        #pragma unroll 4
        for (int d = dg * 16; d < dg * 16 + 16; ++d) {
            float4 wv;
            wv.x = cb[(size_t)k4[0] * D_ + d];
            wv.y = cb[(size_t)k4[1] * D_ + d];
            wv.z = cb[(size_t)k4[2] * D_ + d];
            wv.w = cb[(size_t)k4[3] * D_ + d];
            *reinterpret_cast<float4*>(out + obase + (size_t)d * HW_) = wv;
        }
    }
}

// ================= exact fp32 refine (1 code/thread) + fix-up ==========
__global__ __launch_bounds__(1024)
void vq_refine(const float* __restrict__ x, const float* __restrict__ cb,
               const float* __restrict__ csq, const int* __restrict__ rcount,
               const int* __restrict__ rlist, const float* __restrict__ bdist,
               float* __restrict__ out, float* __restrict__ oidx,
               float* __restrict__ oloss) {
    __shared__ float xv[8][256];
    __shared__ float xsq[8];
    __shared__ float wredv[16][8];
    __shared__ int   wredk[16][8];
    __shared__ int   kfin[8];
    const int tid = threadIdx.x;
    const int code = tid;
    const int wv_i = tid >> 6, lane = tid & 63;
    const int cnt = min(rcount[0], N_);
    for (int base = blockIdx.x * 8; base < cnt; base += gridDim.x * 8) {
        const int m = min(8, cnt - base);
        __syncthreads();
        {   // parallel xv load: thread covers (j, j+4) at d = tid&255
            const int j = tid >> 8, d = tid & 255;
            #pragma unroll
            for (int rep = 0; rep < 2; ++rep) {
                int jj = j + rep * 4;
                float val = 0.f;
                if (jj < m) {
                    int n = rlist[base + jj];
                    int b = n >> 10, hw = n & 1023;
                    val = x[(size_t)b * DHW + (size_t)d * HW_ + hw];
                }
                xv[jj][d] = val;
            }
        }
        __syncthreads();
        if (tid < 256) {   // xsq: 8 groups of 32 lanes (identical chain to before)
            int g = tid >> 5, l = tid & 31;
            float s = 0.f;
            #pragma unroll
            for (int d8 = 0; d8 < 8; ++d8) { float v = xv[g][d8 * 32 + l]; s = fmaf(v, v, s); }
            #pragma unroll
            for (int mm = 1; mm < 32; mm <<= 1) s += __shfl_xor(s, mm, 64);
            if (l == 0) xsq[g] = s;
        }
        __syncthreads();

        float dot[8];
        #pragma unroll
        for (int j = 0; j < 8; ++j) dot[j] = 0.f;

        const float* crow = cb + (size_t)code * D_;
        for (int d0 = 0; d0 < 256; d0 += 8) {
            float xr[8][8];
            #pragma unroll
            for (int j = 0; j < 8; ++j) {
                float4 a = *reinterpret_cast<const float4*>(&xv[j][d0]);
                float4 b = *reinterpret_cast<const float4*>(&xv[j][d0 + 4]);
                xr[j][0] = a.x; xr[j][1] = a.y; xr[j][2] = a.z; xr[j][3] = a.w;
                xr[j][4] = b.x; xr[j][5] = b.y; xr[j][6] = b.z; xr[j][7] = b.w;
            }
            const float4* cr = reinterpret_cast<const float4*>(crow + d0);
            float4 ca = cr[0], cbv = cr[1];
            float cv[8] = { ca.x, ca.y, ca.z, ca.w, cbv.x, cbv.y, cbv.z, cbv.w };
            #pragma unroll
            for (int u = 0; u < 8; ++u)
                #pragma unroll
                for (int j = 0; j < 8; ++j)
                    dot[j] = fmaf(cv[u], xr[j][u], dot[j]);
        }

        const float cs = csq[code];
        #pragma unroll
        for (int j = 0; j < 8; ++j) {
            if (j < m) {
                float v = fmaf(-2.f, dot[j], xsq[j]) + cs;
                int k = code;
                #pragma unroll
                for (int mm = 1; mm < 64; mm <<= 1) {
                    float ov = __shfl_xor(v, mm, 64);
                    int   ok = __shfl_xor(k, mm, 64);
                    if (ov < v || (ov == v && ok < k)) { v = ov; k = ok; }
                }
                if (lane == 0) { wredv[wv_i][j] = v; wredk[wv_i][j] = k; }
            }
        }
        __syncthreads();
        if (tid < m) {
            float v = wredv[0][tid]; int k = wredk[0][tid];
            #pragma unroll
            for (int q = 1; q < 16; ++q) {
                if (wredv[q][tid] < v || (wredv[q][tid] == v && wredk[q][tid] < k)) {
                    v = wredv[q][tid]; k = wredk[q][tid];
                }
            }
            int n = rlist[base + tid];
            kfin[tid] = k;
            oidx[n] = (float)k;
            float delta = (v - bdist[n]) * (1.0f / 8388608.0f);
            atomicAdd(&oloss[0], delta);
            atomicAdd(&oloss[1], delta);
        }
        __syncthreads();
        {   // rewrite out rows for corrected tokens
            const int j = tid >> 8, d = tid & 255;
            #pragma unroll
            for (int rep = 0; rep < 2; ++rep) {
                int jj = j + rep * 4;
                if (jj < m) {
                    int n = rlist[base + jj];
                    int b = n >> 10, hw = n & 1023;
                    out[(size_t)b * DHW + (size_t)d * HW_ + hw] = cb[(size_t)kfin[jj] * D_ + d];
                }
            }
        }
        __syncthreads();
    }
}

extern "C" void kernel_launch(void* const* d_in, const int* in_sizes, int n_in,
                              void* d_out, int out_size, void* d_ws, size_t ws_size,
                              hipStream_t stream) {
    const float* x  = (const float*)d_in[0];
    const float* cb = (const float*)d_in[1];

    float* out   = (float*)d_out;            // 8388608 floats
    float* oidx  = out + 8388608;            // 32768 floats
    float* oloss = out + 8388608 + 32768;    // 2 floats

    uint* wsb = (uint*)d_ws;
    uint4*  cbt2  = (uint4*)wsb;             // 65536 uint4 (1 MB)
    float*  csq   = (float*)(wsb + 262144);  // 1024
    int*    rcount= (int*)  (wsb + 263168);  // 1
    int*    rlist = (int*)  (wsb + 263172);  // 32768
    float*  bdist = (float*)(wsb + 295940);  // 32768

    prep_cb <<<1024, 256, 0, stream>>>(cb, cbt2, csq, rcount, oloss);
    vq_main <<<256, 512, 0, stream>>>(x, cbt2, csq, cb, rcount, rlist, bdist, out, oidx, oloss);
    vq_refine<<<128, 1024, 0, stream>>>(x, cb, csq, rcount, rlist, bdist, out, oidx, oloss);
}